// Round 3
// baseline (694.427 us; speedup 1.0000x reference)
//
#include <hip/hip_runtime.h>
#include <math.h>

// out[b,i,j] = R[i,j] * x[b,i,j] where R is 2x2-block-diagonal:
// only j in {i&~1, (i&~1)+1} are nonzero. So: stream 256 MiB of zeros,
// patch 2 entries per row. Pure store-bandwidth kernel (~41 us floor).
//
// 64 B per thread (4 x 16B), nontemporal streaming stores via native
// ext_vector_type (HIP float4 is a class type the builtin rejects).

constexpr int D = 2048;
constexpr int B = 16;
constexpr long long TOTAL4 = (long long)B * D * D / 4;  // 16B-chunk count

typedef float v4f __attribute__((ext_vector_type(4)));

__global__ __launch_bounds__(256) void rope_block_diag_kernel(
        const float* __restrict__ x, const int* __restrict__ m_ptr,
        float* __restrict__ out) {
    // Each thread owns 4 consecutive 16B chunks (64 B), all within one row
    // (row = 512 chunks; 4-aligned groups never straddle rows).
    const long long f = ((long long)blockIdx.x * blockDim.x + threadIdx.x) * 4;
    const int i  = (int)((f >> 9) & (D - 1));       // row within (D,D)
    const int c0 = (int)(f & (D / 4 - 1));          // first chunk-col of this thread
    const int s  = i >> 2;                          // chunk-col holding row i's 2x2 block

    v4f* __restrict__ op = (v4f*)out + f;

    if (s - c0 >= 0 && s - c0 < 4) {
        // Rare path: one thread per row (1 in 128). Compute rotation, patch.
        const int m = *m_ptr;
        const int p = i >> 1;                       // pair index
        const double ang = (double)m * exp((-2.0 * (double)p / (double)D) * log(10000.0));
        const float c = (float)cos(ang);
        const float sn = (float)sin(ang);

        const v4f xv = ((const v4f*)x)[f + (s - c0)];
        const int o = i & 2;                        // block offset within chunk: 0 or 2
        const float xa = (o == 0) ? xv.x : xv.z;
        const float xb = (o == 0) ? xv.y : xv.w;
        const float va = (i & 1) ? (sn * xa) : (c * xa);
        const float vb = (i & 1) ? (c * xb) : (-sn * xb);
        v4f pv = (v4f)(0.f);
        if (o == 0) { pv.x = va; pv.y = vb; }
        else        { pv.z = va; pv.w = vb; }

        #pragma unroll
        for (int k = 0; k < 4; ++k) {
            v4f v = (k == s - c0) ? pv : (v4f)(0.f);
            op[k] = v;
        }
    } else {
        // Hot path: pure streaming zero-stores, nontemporal (no L2 allocate).
        const v4f z = (v4f)(0.f);
        #pragma unroll
        for (int k = 0; k < 4; ++k) {
            __builtin_nontemporal_store(z, op + k);
        }
    }
}

extern "C" void kernel_launch(void* const* d_in, const int* in_sizes, int n_in,
                              void* d_out, int out_size, void* d_ws, size_t ws_size,
                              hipStream_t stream) {
    const float* x     = (const float*)d_in[0];
    const int*   m_ptr = (const int*)d_in[1];
    float*       out   = (float*)d_out;

    const int block = 256;
    const long long nthreads = TOTAL4 / 4;          // 4 chunks per thread
    const long long grid = nthreads / block;        // exact
    rope_block_diag_kernel<<<(unsigned)grid, block, 0, stream>>>(x, m_ptr, out);
}

// Round 4
// 415.290 us; speedup vs baseline: 1.6722x; 1.6722x over previous
//
#include <hip/hip_runtime.h>
#include <math.h>

// out[b,i,j] = R[i,j] * x[b,i,j] where R is 2x2-block-diagonal:
// only j in {i&~1, (i&~1)+1} are nonzero. So: stream 256 MiB of zeros,
// patch 2 entries per row. Pure store-bandwidth kernel (~41 us floor).
//
// R2 lesson: nontemporal stores bypass L2 write-combining -> 2.6x write
// amplification at HBM (676 MB observed) and 1.8 TB/s. Use REGULAR stores
// (same path as the 6.5 TB/s fill kernel). 64 B per thread.

constexpr int D = 2048;
constexpr int B = 16;
constexpr long long TOTAL4 = (long long)B * D * D / 4;  // 16B-chunk count

typedef float v4f __attribute__((ext_vector_type(4)));

__global__ __launch_bounds__(256) void rope_block_diag_kernel(
        const float* __restrict__ x, const int* __restrict__ m_ptr,
        float* __restrict__ out) {
    // Each thread owns 4 consecutive 16B chunks (64 B), all within one row
    // (row = 512 chunks; 4-aligned groups never straddle rows).
    const long long f = ((long long)blockIdx.x * blockDim.x + threadIdx.x) * 4;
    const int i  = (int)((f >> 9) & (D - 1));       // row within (D,D)
    const int c0 = (int)(f & (D / 4 - 1));          // first chunk-col of this thread
    const int s  = i >> 2;                          // chunk-col holding row i's 2x2 block
    const int r  = s - c0;                          // which of my 4 chunks has the block

    v4f* __restrict__ op = (v4f*)out + f;

    v4f v0 = (v4f)(0.f), v1 = (v4f)(0.f), v2 = (v4f)(0.f), v3 = (v4f)(0.f);

    if (r >= 0 && r < 4) {
        // Rare path: one thread per row (1 in 128). Compute rotation, patch.
        const int m = *m_ptr;
        const int p = i >> 1;                       // pair index
        const double ang = (double)m * exp((-2.0 * (double)p / (double)D) * log(10000.0));
        const float c = (float)cos(ang);
        const float sn = (float)sin(ang);

        const v4f xv = ((const v4f*)x)[f + r];
        const int o = i & 2;                        // block offset within chunk: 0 or 2
        const float xa = (o == 0) ? xv.x : xv.z;
        const float xb = (o == 0) ? xv.y : xv.w;
        const float va = (i & 1) ? (sn * xa) : (c * xa);
        const float vb = (i & 1) ? (c * xb) : (-sn * xb);
        v4f pv = (v4f)(0.f);
        if (o == 0) { pv.x = va; pv.y = vb; }
        else        { pv.z = va; pv.w = vb; }
        if (r == 0) v0 = pv; else if (r == 1) v1 = pv;
        else if (r == 2) v2 = pv; else v3 = pv;
    }

    op[0] = v0;
    op[1] = v1;
    op[2] = v2;
    op[3] = v3;
}

extern "C" void kernel_launch(void* const* d_in, const int* in_sizes, int n_in,
                              void* d_out, int out_size, void* d_ws, size_t ws_size,
                              hipStream_t stream) {
    const float* x     = (const float*)d_in[0];
    const int*   m_ptr = (const int*)d_in[1];
    float*       out   = (float*)d_out;

    const int block = 256;
    const long long nthreads = TOTAL4 / 4;          // 4 chunks per thread
    const long long grid = nthreads / block;        // exact
    rope_block_diag_kernel<<<(unsigned)grid, block, 0, stream>>>(x, m_ptr, out);
}

// Round 5
// 374.887 us; speedup vs baseline: 1.8524x; 1.1078x over previous
//
#include <hip/hip_runtime.h>
#include <math.h>

// out[b,i,j] = R[i,j] * x[b,i,j] where R is 2x2-block-diagonal:
// only j in {i&~1, (i&~1)+1} are nonzero. Stream 256 MiB of zeros,
// patch 2 entries per row. Pure store-bandwidth kernel (~41 us floor).
//
// R2 lesson: nontemporal stores bypass L2 write-combining -> 2.6x HBM write
// amplification. R3 lesson: 4 CONSECUTIVE chunks/thread makes each store
// instruction a 64B-stride scatter (64 cache lines @ 16B each) -> regressed.
// This version: 4 chunks/thread interleaved at blockDim stride, so every
// store instruction is lane-contiguous (64 lanes x 16B = 1KB/instr).

constexpr int D = 2048;
constexpr int B = 16;
constexpr long long TOTAL4 = (long long)B * D * D / 4;  // 16B-chunk count
constexpr int CHUNKS_PER_THREAD = 4;

typedef float v4f __attribute__((ext_vector_type(4)));

__global__ __launch_bounds__(256) void rope_block_diag_kernel(
        const float* __restrict__ x, const int* __restrict__ m_ptr,
        float* __restrict__ out) {
    const long long base = (long long)blockIdx.x * (256 * CHUNKS_PER_THREAD) + threadIdx.x;

    #pragma unroll
    for (int k = 0; k < CHUNKS_PER_THREAD; ++k) {
        const long long cs = base + (long long)k * 256;   // chunk index
        const int c  = (int)(cs & (D / 4 - 1));           // chunk-col in row: 0..511
        const int i  = (int)((cs >> 9) & (D - 1));        // row within (D,D)

        v4f v = (v4f)(0.f);
        if (c == (i >> 2)) {
            // Rare path (1 thread-store in 512): compute rotation, patch.
            const int m = *m_ptr;
            const int p = i >> 1;                         // pair index
            const double ang = (double)m * exp((-2.0 * (double)p / (double)D) * log(10000.0));
            const float co = (float)cos(ang);
            const float sn = (float)sin(ang);

            const v4f xv = ((const v4f*)x)[cs];
            const int o = i & 2;                          // block offset in chunk: 0 or 2
            const float xa = (o == 0) ? xv.x : xv.z;
            const float xb = (o == 0) ? xv.y : xv.w;
            const float va = (i & 1) ? (sn * xa) : (co * xa);
            const float vb = (i & 1) ? (co * xb) : (-sn * xb);
            if (o == 0) { v.x = va; v.y = vb; }
            else        { v.z = va; v.w = vb; }
        }
        ((v4f*)out)[cs] = v;
    }
}

extern "C" void kernel_launch(void* const* d_in, const int* in_sizes, int n_in,
                              void* d_out, int out_size, void* d_ws, size_t ws_size,
                              hipStream_t stream) {
    const float* x     = (const float*)d_in[0];
    const int*   m_ptr = (const int*)d_in[1];
    float*       out   = (float*)d_out;

    const int block = 256;
    const long long grid = TOTAL4 / (block * CHUNKS_PER_THREAD);  // 16384, exact
    rope_block_diag_kernel<<<(unsigned)grid, block, 0, stream>>>(x, m_ptr, out);
}

// Round 6
// 369.261 us; speedup vs baseline: 1.8806x; 1.0152x over previous
//
#include <hip/hip_runtime.h>
#include <math.h>

// out[b,i,j] = R[i,j] * x[b,i,j] where R is 2x2-block-diagonal:
// only j in {i&~1, (i&~1)+1} are nonzero. Stream 256 MiB of zeros,
// patch 2 entries per row. Pure store-bandwidth kernel (~41 us floor).
//
// Session lessons baked in:
//  - R2: nontemporal stores bypass L2 write-combining -> 2.6x HBM write
//    amplification (676 MB vs 268 MB) and 1.8 TB/s. Regular stores win.
//  - R3: 4 CONSECUTIVE chunks/thread -> each store instr is a 64B-stride
//    scatter across 64 cache lines -> regressed. Lane-contiguity per
//    INSTRUCTION is what matters.
//  - R4: 4 interleaved chunks/thread -> ~+7us vs 1 chunk/thread (extra
//    index math, no benefit at this oversubscription). Simplest is best.
// Best measured: one 16B chunk per thread (R0 structure), 368.5 us total
// (~53 us own time vs ~41 us floor + launch overhead; rest is harness).

constexpr int D = 2048;
constexpr int B = 16;
constexpr long long TOTAL4 = (long long)B * D * D / 4;  // 16B-chunk count

typedef float v4f __attribute__((ext_vector_type(4)));

__global__ __launch_bounds__(256) void rope_block_diag_kernel(
        const float* __restrict__ x, const int* __restrict__ m_ptr,
        float* __restrict__ out) {
    const long long idx = (long long)blockIdx.x * blockDim.x + threadIdx.x;
    const int c = (int)(idx & (D / 4 - 1));           // chunk-col in row: 0..511
    const int i = (int)((idx >> 9) & (D - 1));        // row within (D,D)

    v4f v = (v4f)(0.f);

    // Row i's 2x2 block lives in chunk-col i>>2. One chunk per row.
    if (c == (i >> 2)) {
        const int m = *m_ptr;
        const int p = i >> 1;                         // pair index 0..1023
        const double ang = (double)m * exp((-2.0 * (double)p / (double)D) * log(10000.0));
        const float co = (float)cos(ang);
        const float sn = (float)sin(ang);

        const v4f xv = ((const v4f*)x)[idx];
        const int o = i & 2;                          // block offset in chunk: 0 or 2
        const float xa = (o == 0) ? xv.x : xv.z;
        const float xb = (o == 0) ? xv.y : xv.w;
        const float va = (i & 1) ? (sn * xa) : (co * xa);
        const float vb = (i & 1) ? (co * xb) : (-sn * xb);
        if (o == 0) { v.x = va; v.y = vb; }
        else        { v.z = va; v.w = vb; }
    }

    ((v4f*)out)[idx] = v;
}

extern "C" void kernel_launch(void* const* d_in, const int* in_sizes, int n_in,
                              void* d_out, int out_size, void* d_ws, size_t ws_size,
                              hipStream_t stream) {
    const float* x     = (const float*)d_in[0];
    const int*   m_ptr = (const int*)d_in[1];
    float*       out   = (float*)d_out;

    const int block = 256;
    const long long grid = TOTAL4 / block;            // 65536, exact
    rope_block_diag_kernel<<<(unsigned)grid, block, 0, stream>>>(x, m_ptr, out);
}